// Round 6
// baseline (12164.233 us; speedup 1.0000x reference)
//
#include <hip/hip_runtime.h>
#include <math.h>

#define N_NODES 10000
#define N_EDGES 320000

// persistent-grid geometry (r1-proven co-resident): 512 blocks x 512 threads
// = 4096 waves, __launch_bounds__(512,4) -> 4 waves/SIMD -> 2 blocks/CU x 256.
#define NBLK 512
#define NTHR 512
#define NWAVES 4096

// ---------------- barrier state ----------------
// 16-way striped monotonic arrival tree; each word on its own 256-B line.
struct alignas(256) PadInt { int v; int _p[63]; };
struct Bar { PadInt leaf[16]; PadInt root; PadInt go[16]; };  // 33 * 256 B
#define BAR_INTS (33 * 64)                   // ints per Bar
#define BAR_REGION_INTS (3 * BAR_INTS + 64)  // 3 layer barriers + abort word

// ---------------- setup kernels ----------------

__global__ void k_init(float* deg, int* cnt, int* fill, int* barmem, int n) {
    int i = blockIdx.x * blockDim.x + threadIdx.x;
    if (i < n) { deg[i] = 0.f; cnt[i] = 0; fill[i] = 0; }
    if (i < BAR_REGION_INTS) barmem[i] = 0;
}

__global__ void k_deg(const int* __restrict__ ei, const float* __restrict__ w,
                      float* deg, int E) {
    int e = blockIdx.x * blockDim.x + threadIdx.x;
    if (e < E) atomicAdd(&deg[ei[e]], w[e]);
}

__global__ void k_dis(float* deg, int n) {
    int i = blockIdx.x * blockDim.x + threadIdx.x;
    if (i < n) {
        float d = deg[i];
        deg[i] = (d > 0.f) ? (float)(1.0 / sqrt((double)d)) : 0.f;
    }
}

__global__ void k_norm(const int* __restrict__ ei, const float* __restrict__ w,
                       const float* __restrict__ dis, float* __restrict__ normw,
                       int* cnt, int E) {
    int e = blockIdx.x * blockDim.x + threadIdx.x;
    if (e < E) {
        int s = ei[e], d = ei[E + e];
        normw[e] = -dis[s] * w[e] * dis[d];
        atomicAdd(&cnt[d], 1);
    }
}

// single-block exclusive scan over counts -> rowptr[0..n]
__global__ void k_scan(const int* __restrict__ cnt, int* __restrict__ rowptr, int n) {
    __shared__ int part[1024];
    const int PER = 10;  // 1024*10 >= n
    int t = threadIdx.x;
    int base = t * PER;
    int local[PER];
    int s = 0;
    for (int j = 0; j < PER; j++) {
        int idx = base + j;
        int v = (idx < n) ? cnt[idx] : 0;
        local[j] = v; s += v;
    }
    part[t] = s;
    __syncthreads();
    for (int off = 1; off < 1024; off <<= 1) {
        int v = part[t];
        int u = (t >= off) ? part[t - off] : 0;
        __syncthreads();
        part[t] = v + u;
        __syncthreads();
    }
    int excl = (t > 0) ? part[t - 1] : 0;
    for (int j = 0; j < PER; j++) {
        int idx = base + j;
        if (idx < n) rowptr[idx] = excl;
        excl += local[j];
    }
    if (t == 1023) rowptr[n] = part[1023];
}

// pair CSR: {src byte-offset (stride-64 rows), norm bits}
__global__ void k_fill(const int* __restrict__ ei, const float* __restrict__ normw,
                       const int* __restrict__ rowptr, int* fill,
                       int2* __restrict__ pr, int E) {
    int e = blockIdx.x * blockDim.x + threadIdx.x;
    if (e < E) {
        int d = ei[E + e];
        int pos = atomicAdd(&fill[d], 1);
        int idx = rowptr[d] + pos;
        pr[idx] = make_int2(ei[e] << 8, __float_as_int(normw[e]));
    }
}

// ---------------- coherent access helpers ----------------
// Agent-scope relaxed atomics -> global_load/store sc0 sc1: bypass L1/L2,
// serviced at the coherence point. NO cache fences needed anywhere.
__device__ __forceinline__ void pub4(float* p, float v) {
    __hip_atomic_store(p, v, __ATOMIC_RELAXED, __HIP_MEMORY_SCOPE_AGENT);
}
template <bool COH>
__device__ __forceinline__ float ld4(const char* p) {
    if constexpr (COH)
        return __hip_atomic_load((const float*)(const void*)p,
                                 __ATOMIC_RELAXED, __HIP_MEMORY_SCOPE_AGENT);
    else
        return *(const float*)(const void*)p;
}

// ---------------- grid barrier v4 (fence-free) ----------------
// Correctness: every wave drains vmcnt(0) (sc1 publishes ack from the
// coherence point) before __syncthreads; tid0 arrival add is therefore
// ordered after ALL the block's publishes. go>=phase implies all 512 blocks
// arrived, hence all publishes globally visible. Readers use sc1 loads, so
// no stale L1/L2 lines can be observed -> no acquire invalidate needed.
__device__ __forceinline__ bool gridbar(Bar* __restrict__ B, int* __restrict__ abortf,
                                        int phase) {
    __shared__ int ok_s;
    asm volatile("s_waitcnt vmcnt(0)" ::: "memory");
    __syncthreads();
    if (threadIdx.x == 0) {
        int s = blockIdx.x & 15;
        int old = __hip_atomic_fetch_add(&B->leaf[s].v, 1,
                                         __ATOMIC_RELAXED, __HIP_MEMORY_SCOPE_AGENT);
        if (old + 1 == phase * (NBLK / 16)) {  // last arriver of this stripe
            int r = __hip_atomic_fetch_add(&B->root.v, 1,
                                           __ATOMIC_RELAXED, __HIP_MEMORY_SCOPE_AGENT);
            if (r + 1 == phase * 16) {  // last stripe: publish
#pragma unroll
                for (int j = 0; j < 16; j++)
                    __hip_atomic_store(&B->go[j].v, phase,
                                       __ATOMIC_RELAXED, __HIP_MEMORY_SCOPE_AGENT);
            }
        }
        int ok = 1, spins = 0;
        while (__hip_atomic_load(&B->go[s].v, __ATOMIC_RELAXED,
                                 __HIP_MEMORY_SCOPE_AGENT) < phase) {
            __builtin_amdgcn_s_sleep(2);
            if ((++spins & 255) == 0) {
                if (__hip_atomic_load(abortf, __ATOMIC_RELAXED,
                                      __HIP_MEMORY_SCOPE_AGENT)) { ok = 0; break; }
                if (spins > (1 << 19)) {  // ~0.3 s: residency failure -> abort all
                    __hip_atomic_store(abortf, 1, __ATOMIC_RELAXED,
                                       __HIP_MEMORY_SCOPE_AGENT);
                    ok = 0; break;
                }
            }
        }
        ok_s = ok;
    }
    __syncthreads();
    return ok_s != 0;
}

// ---------------- gathers ----------------
// wide: lane = channel (stride-64 float rows). Batch-8 pipelined loads.
template <bool COH>
__device__ __forceinline__ float gather_w(const char* __restrict__ tb,
                                          const int2* __restrict__ pr,
                                          int rb, int dg, int lane4) {
    float agg = 0.f;
    int e = 0;
    for (; e + 8 <= dg; e += 8) {
        int2 p[8]; float v[8];
#pragma unroll
        for (int u = 0; u < 8; u++) p[u] = pr[rb + e + u];
#pragma unroll
        for (int u = 0; u < 8; u++)
            v[u] = ld4<COH>(tb + (unsigned)p[u].x + lane4);
#pragma unroll
        for (int u = 0; u < 8; u++)
            agg = fmaf(__int_as_float(p[u].y), v[u], agg);
    }
    if (e < dg) {  // masked batch-8 tail: stays pipelined
        int2 p[8]; float v[8];
#pragma unroll
        for (int u = 0; u < 8; u++) p[u] = pr[(e + u < dg) ? (rb + e + u) : rb];
#pragma unroll
        for (int u = 0; u < 8; u++)
            v[u] = ld4<COH>(tb + (unsigned)p[u].x + lane4);
#pragma unroll
        for (int u = 0; u < 8; u++) {
            float w = (e + u < dg) ? __int_as_float(p[u].y) : 0.f;
            agg = fmaf(w, v[u], agg);
        }
    }
    return agg;
}

// narrow (stride-4 float rows): lane = eo*4+lc, 16 edges in parallel, batch-2.
// pair offset is src<<8; stride-4 byte offset = src<<4 = off>>4.
template <bool COH>
__device__ __forceinline__ float gather_n(const char* __restrict__ tb,
                                          const int2* __restrict__ pr,
                                          int rb, int dg, int lc4, int eo) {
    float agg = 0.f;
    int e = eo;
    for (; e + 32 <= dg; e += 32) {
        int2 p0 = pr[rb + e];
        int2 p1 = pr[rb + e + 16];
        float v0 = ld4<COH>(tb + ((unsigned)p0.x >> 4) + lc4);
        float v1 = ld4<COH>(tb + ((unsigned)p1.x >> 4) + lc4);
        agg = fmaf(__int_as_float(p0.y), v0, agg);
        agg = fmaf(__int_as_float(p1.y), v1, agg);
    }
    for (; e < dg; e += 16) {
        int2 p = pr[rb + e];
        agg = fmaf(__int_as_float(p.y),
                   ld4<COH>(tb + ((unsigned)p.x >> 4) + lc4), agg);
    }
    agg += __shfl_xor(agg, 4);
    agg += __shfl_xor(agg, 8);
    agg += __shfl_xor(agg, 16);
    agg += __shfl_xor(agg, 32);
    return agg;  // channel lc, replicated across eo groups
}

// ---------------- dense: acc(lane=o) += sum_c t2(c) * W[c][o] ----------------
template <int CI, int CO>
__device__ __forceinline__ void dense(float& acc, float t2v,
                                      const float* __restrict__ Wk, int lane) {
#pragma unroll
    for (int c = 0; c < CI; c++) {
        float tb = __int_as_float(__builtin_amdgcn_readlane(__float_as_int(t2v), c));
        float wv;
        if (CO < 64) wv = (lane < CO) ? Wk[c * CO + lane] : 0.f;
        else         wv = Wk[c * CO + lane];
        acc = fmaf(tb, wv, acc);
    }
}

// ---------------- persistent layer kernels ----------------
// Each wave owns 2-3 nodes for the whole K-recurrence; acc / T_{k-2} / T_{k-1}
// (own-node) stay in registers; only T_{k-1} rows are published via sc1
// write-through stores to a 2-deep rotating buffer, gathered via sc1 loads;
// one fence-free grid barrier per step.

// wide: CI in {64,60}, rows stride 64. LAST 1: silu->outp(n x 64); 2: silu+W4+sigmoid->outp(n).
template <int CI, int CO, int KK, int LAST>
__global__ __launch_bounds__(NTHR, 4) void layer_wide(
    const int* __restrict__ rowptr, const int2* __restrict__ pr,
    const float* __restrict__ hin,
    float* __restrict__ tA, float* __restrict__ tB,
    const float* __restrict__ W, const float* __restrict__ bias,
    const float* __restrict__ W4, float* __restrict__ outp,
    Bar* __restrict__ bar, int* __restrict__ abortf)
{
    int tid = threadIdx.x;
    int lane = tid & 63;
    int lane4 = lane * 4;
    int wid = blockIdx.x * (NTHR / 64) + (tid >> 6);  // 0..4095

    int n0 = wid;
    int n1 = wid + NWAVES;
    bool has2 = wid < (N_NODES - 2 * NWAVES);  // 1808
    int n2 = wid + 2 * NWAVES;

    int rb0 = rowptr[n0], dg0 = rowptr[n0 + 1] - rb0;
    int rb1 = rowptr[n1], dg1 = rowptr[n1 + 1] - rb1;
    int rb2 = 0, dg2 = 0;
    if (has2) { rb2 = rowptr[n2]; dg2 = rowptr[n2 + 1] - rb2; }

    float acc0, acc1, acc2 = 0.f;
    float p0, p1, p2 = 0.f;   // T_{k-2} own value
    float q0, q1, q2 = 0.f;   // T_{k-1} own value

#define K01W(nid, rb, dg, acc, t0v, t1v) {                             \
        float hr = hin[(nid) * 64 + lane];                             \
        float a = (lane < CO) ? bias[lane] : 0.f;                      \
        dense<CI, CO>(a, hr, W, lane);                                 \
        float g = gather_w<false>((const char*)hin, pr, rb, dg, lane4);\
        dense<CI, CO>(a, g, W + CI * CO, lane);                        \
        pub4(&tB[(nid) * 64 + lane], g);                               \
        acc = a; t0v = hr; t1v = g; }

#define STEPW(nid, rb, dg, acc, t0v, t1v) {                            \
        float g = gather_w<true>((const char*)rd, pr, rb, dg, lane4);  \
        float t2 = fmaf(2.f, g, -t0v);                                 \
        dense<CI, CO>(acc, t2, Wk, lane);                              \
        if (!lastk) { pub4(&wr[(nid) * 64 + lane], t2); t0v = t1v; t1v = t2; } }

    int phase = 0;
    K01W(n0, rb0, dg0, acc0, p0, q0);
    K01W(n1, rb1, dg1, acc1, p1, q1);
    if (has2) K01W(n2, rb2, dg2, acc2, p2, q2);
    if (!gridbar(bar, abortf, ++phase)) return;

    for (int k = 2; k < KK; k++) {
        const float* rd = (k & 1) ? tA : tB;   // buf[(k-1)%2]
        float* wr = (k & 1) ? tB : tA;         // buf[k%2]
        const float* Wk = W + (size_t)k * (CI * CO);
        const bool lastk = (k == KK - 1);
        STEPW(n0, rb0, dg0, acc0, p0, q0);
        STEPW(n1, rb1, dg1, acc1, p1, q1);
        if (has2) STEPW(n2, rb2, dg2, acc2, p2, q2);
        if (!lastk) { if (!gridbar(bar, abortf, ++phase)) return; }
    }

#define EPIW(nid, acc) {                                           \
        float a = acc;                                             \
        if (LAST == 1) {                                           \
            outp[(nid) * 64 + lane] = a / (1.f + expf(-a));        \
        } else {                                                   \
            float h = a / (1.f + expf(-a));                        \
            float w4 = (lane < 30) ? W4[lane] : 0.f;               \
            float pp = h * w4;                                     \
            pp += __shfl_xor(pp, 1);                               \
            pp += __shfl_xor(pp, 2);                               \
            pp += __shfl_xor(pp, 4);                               \
            pp += __shfl_xor(pp, 8);                               \
            pp += __shfl_xor(pp, 16);                              \
            pp += __shfl_xor(pp, 32);                              \
            if (lane == 0) outp[nid] = 1.f / (1.f + expf(-pp));    \
        } }

    EPIW(n0, acc0);
    EPIW(n1, acc1);
    if (has2) EPIW(n2, acc2);
#undef K01W
#undef STEPW
#undef EPIW
}

// narrow: layer 1 (4 -> 64), rows stride 4. Output: silu -> outp (n x 64).
template <int KK>
__global__ __launch_bounds__(NTHR, 4) void layer_narrow(
    const int* __restrict__ rowptr, const int2* __restrict__ pr,
    const float* __restrict__ xin,
    float* __restrict__ tA, float* __restrict__ tB,
    const float* __restrict__ W, const float* __restrict__ bias,
    float* __restrict__ outp,
    Bar* __restrict__ bar, int* __restrict__ abortf)
{
    int tid = threadIdx.x;
    int lane = tid & 63;
    int lc = lane & 3, eo = lane >> 2, lc4 = lc * 4;
    int wid = blockIdx.x * (NTHR / 64) + (tid >> 6);

    int n0 = wid;
    int n1 = wid + NWAVES;
    bool has2 = wid < (N_NODES - 2 * NWAVES);
    int n2 = wid + 2 * NWAVES;

    int rb0 = rowptr[n0], dg0 = rowptr[n0 + 1] - rb0;
    int rb1 = rowptr[n1], dg1 = rowptr[n1 + 1] - rb1;
    int rb2 = 0, dg2 = 0;
    if (has2) { rb2 = rowptr[n2]; dg2 = rowptr[n2 + 1] - rb2; }

    float acc0, acc1, acc2 = 0.f;
    float p0, p1, p2 = 0.f;
    float q0, q1, q2 = 0.f;

#define K01N(nid, rb, dg, acc, t0v, t1v) {                               \
        float xr = xin[(nid) * 4 + lc];                                  \
        float a = bias[lane];                                            \
        dense<4, 64>(a, xr, W, lane);                                    \
        float g = gather_n<false>((const char*)xin, pr, rb, dg, lc4, eo);\
        dense<4, 64>(a, g, W + 4 * 64, lane);                            \
        if (lane < 4) pub4(&tB[(nid) * 4 + lane], g);                    \
        acc = a; t0v = xr; t1v = g; }

#define STEPN(nid, rb, dg, acc, t0v, t1v) {                              \
        float g = gather_n<true>((const char*)rd, pr, rb, dg, lc4, eo);  \
        float t2 = fmaf(2.f, g, -t0v);                                   \
        dense<4, 64>(acc, t2, Wk, lane);                                 \
        if (!lastk) {                                                    \
            if (lane < 4) pub4(&wr[(nid) * 4 + lane], t2);               \
            t0v = t1v; t1v = t2; } }

    int phase = 0;
    K01N(n0, rb0, dg0, acc0, p0, q0);
    K01N(n1, rb1, dg1, acc1, p1, q1);
    if (has2) K01N(n2, rb2, dg2, acc2, p2, q2);
    if (!gridbar(bar, abortf, ++phase)) return;

    for (int k = 2; k < KK; k++) {
        const float* rd = (k & 1) ? tA : tB;
        float* wr = (k & 1) ? tB : tA;
        const float* Wk = W + (size_t)k * (4 * 64);
        const bool lastk = (k == KK - 1);
        STEPN(n0, rb0, dg0, acc0, p0, q0);
        STEPN(n1, rb1, dg1, acc1, p1, q1);
        if (has2) STEPN(n2, rb2, dg2, acc2, p2, q2);
        if (!lastk) { if (!gridbar(bar, abortf, ++phase)) return; }
    }

    outp[n0 * 64 + lane] = acc0 / (1.f + expf(-acc0));
    outp[n1 * 64 + lane] = acc1 / (1.f + expf(-acc1));
    if (has2) outp[n2 * 64 + lane] = acc2 / (1.f + expf(-acc2));
#undef K01N
#undef STEPN
}

// ---------------- host ----------------

extern "C" void kernel_launch(void* const* d_in, const int* in_sizes, int n_in,
                              void* d_out, int out_size, void* d_ws, size_t ws_size,
                              hipStream_t stream) {
    const float* x  = (const float*)d_in[0];
    const int*   ei = (const int*)d_in[1];
    const float* ew = (const float*)d_in[2];
    const float* W1 = (const float*)d_in[3];
    const float* b1 = (const float*)d_in[4];
    const float* W2 = (const float*)d_in[5];
    const float* b2 = (const float*)d_in[6];
    const float* W3 = (const float*)d_in[7];
    const float* b3 = (const float*)d_in[8];
    const float* W4 = (const float*)d_in[9];
    float* out = (float*)d_out;

    const int n = N_NODES, E = N_EDGES;

    char* ws = (char*)d_ws;
    size_t off = 0;
    auto alloc = [&](size_t bytes) -> void* {
        void* p = ws + off;
        off += (bytes + 255) & ~(size_t)255;
        return p;
    };
    float* deg    = (float*)alloc(n * 4);     // becomes dis in-place
    int*   cnt    = (int*)alloc(n * 4);
    int*   fill   = (int*)alloc(n * 4);
    int*   rowptr = (int*)alloc((n + 4) * 4);
    float* normw  = (float*)alloc((size_t)E * 4);
    int2*  pr     = (int2*)alloc((size_t)E * 8);
    int*   barmem = (int*)alloc(BAR_REGION_INTS * 4);
    float* t4a  = (float*)alloc(n * 4 * 4);
    float* t4b  = (float*)alloc(n * 4 * 4);
    float* tba  = (float*)alloc(n * 64 * 4);
    float* tbb  = (float*)alloc(n * 64 * 4);
    float* h1   = (float*)alloc(n * 64 * 4);
    float* h2   = (float*)alloc(n * 64 * 4);
    (void)ws_size; (void)n_in; (void)in_sizes; (void)out_size;

    Bar* bar1 = (Bar*)barmem;
    Bar* bar2 = bar1 + 1;
    Bar* bar3 = bar1 + 2;
    int* abortf = barmem + 3 * BAR_INTS;

    // ---- preprocessing: degree, norm, dst-sorted pair-CSR ----
    k_init<<<(n + 255) / 256, 256, 0, stream>>>(deg, cnt, fill, barmem, n);
    k_deg <<<(E + 255) / 256, 256, 0, stream>>>(ei, ew, deg, E);
    k_dis <<<(n + 255) / 256, 256, 0, stream>>>(deg, n);
    k_norm<<<(E + 255) / 256, 256, 0, stream>>>(ei, ew, deg, normw, cnt, E);
    k_scan<<<1, 1024, 0, stream>>>(cnt, rowptr, n);
    k_fill<<<(E + 255) / 256, 256, 0, stream>>>(ei, normw, rowptr, fill, pr, E);

    // ---- Layer 1: K=120, 4 -> 64, silu -> h1 (persistent, fence-free) ----
    layer_narrow<120><<<NBLK, NTHR, 0, stream>>>(
        rowptr, pr, x, t4a, t4b, W1, b1, h1, bar1, abortf);

    // ---- Layer 2: K=120, 64 -> 60, silu -> h2 (persistent, fence-free) ----
    layer_wide<64, 60, 120, 1><<<NBLK, NTHR, 0, stream>>>(
        rowptr, pr, h1, tba, tbb, W2, b2, nullptr, h2, bar2, abortf);

    // ---- Layer 3 (K=20, 60 -> 30, silu) + fused Layer 4 (30 -> 1, sigmoid) ----
    layer_wide<60, 30, 20, 2><<<NBLK, NTHR, 0, stream>>>(
        rowptr, pr, h2, tba, tbb, W3, b3, W4, out, bar3, abortf);
}